// Round 7
// baseline (199.739 us; speedup 1.0000x reference)
//
#include <hip/hip_runtime.h>
#include <hip/hip_bf16.h>

typedef short bf16x8 __attribute__((ext_vector_type(8)));
typedef float f32x16 __attribute__((ext_vector_type(16)));
typedef unsigned short ushort8 __attribute__((ext_vector_type(8)));
typedef unsigned short ushort4v __attribute__((ext_vector_type(4)));

#define CDIM 256
#define NPIX 1024
#define NB 16
#define NH 8
#define HD 32
// scale * log2(e): softmax done in exp2 domain
#define QSCALE (0.17677669529663687f * 1.4426950408889634f)

static __device__ inline unsigned short f2bf(float f) {
    __hip_bfloat16 h = __float2bfloat16(f);
    return *reinterpret_cast<unsigned short*>(&h);
}

// ---------------------------------------------------------------------------
// Kernel 1a: partial sums for GroupNorm stats. grid (slice=16, b=16).
// ---------------------------------------------------------------------------
__global__ __launch_bounds__(256)
void gn_partial_kernel(const float* __restrict__ x, float* __restrict__ partial) {
    const int slice = blockIdx.x, b = blockIdx.y;
    const float4* xb = (const float4*)(x + (size_t)b * CDIM * NPIX + slice * 16384);
    const int tid = threadIdx.x;
    float s = 0.f, ss = 0.f;
    #pragma unroll
    for (int i = 0; i < 16; ++i) {
        float4 v = xb[tid + i * 256];
        s  += v.x + v.y + v.z + v.w;
        ss += v.x * v.x + v.y * v.y + v.z * v.z + v.w * v.w;
    }
    __shared__ float r0[256], r1[256];
    r0[tid] = s; r1[tid] = ss;
    __syncthreads();
    for (int st = 128; st > 0; st >>= 1) {
        if (tid < st) { r0[tid] += r0[tid + st]; r1[tid] += r1[tid + st]; }
        __syncthreads();
    }
    if (tid == 0) {
        partial[(b * 16 + slice) * 2 + 0] = r0[0];
        partial[(b * 16 + slice) * 2 + 1] = r1[0];
    }
}

// Kernel 1b: finalize stats. grid 16 blocks x 64 thr.
__global__ __launch_bounds__(64)
void gn_final_kernel(const float* __restrict__ partial, float* __restrict__ stats) {
    const int b = blockIdx.x, t = threadIdx.x;
    float s = 0.f, ss = 0.f;
    if (t < 16) { s = partial[(b * 16 + t) * 2]; ss = partial[(b * 16 + t) * 2 + 1]; }
    #pragma unroll
    for (int m = 8; m >= 1; m >>= 1) { s += __shfl_xor(s, m); ss += __shfl_xor(ss, m); }
    if (t == 0) {
        const float inv_n = 1.0f / (float)(CDIM * NPIX);
        float mean = s * inv_n;
        float var  = ss * inv_n - mean * mean;
        stats[b * 2 + 0] = mean;
        stats[b * 2 + 1] = rsqrtf(var + 1e-5f);
    }
}

// ---------------------------------------------------------------------------
// Kernel 2: weights f32 -> bf16 (qkv_w then proj_w).
// ---------------------------------------------------------------------------
__global__ __launch_bounds__(256)
void wconv_kernel(const float* __restrict__ qw, const float* __restrict__ pw,
                  unsigned short* __restrict__ wqb, unsigned short* __restrict__ wpb) {
    int idx = blockIdx.x * 256 + threadIdx.x;
    #pragma unroll
    for (int i = 0; i < 4; ++i) {
        int j = idx + i * 65536;
        if (j < 768 * 256) wqb[j] = f2bf(qw[j]);
        else               wpb[j - 768 * 256] = f2bf(pw[j - 768 * 256]);
    }
}

// ---------------------------------------------------------------------------
// Kernel 3: xnbT[b][p][c] bf16 = GroupNorm-affine(x[b][c][p]).  64x64 tiles.
// ---------------------------------------------------------------------------
__global__ __launch_bounds__(256)
void xnbt_kernel(const float* __restrict__ x, const float* __restrict__ gnw,
                 const float* __restrict__ gnb, const float* __restrict__ stats,
                 unsigned short* __restrict__ xnbT) {
    const int p0 = blockIdx.x * 64, c0 = blockIdx.y * 64, b = blockIdx.z;
    const int q = threadIdx.x >> 6, l = threadIdx.x & 63;
    const float mean = stats[b * 2], rstd = stats[b * 2 + 1];
    __shared__ float L[64][65];
    const float* xb = x + (size_t)b * CDIM * NPIX;
    #pragma unroll
    for (int i = 0; i < 16; ++i) {
        int ci = q * 16 + i;
        int c = c0 + ci;
        float sc = rstd * gnw[c];
        float sh = gnb[c] - mean * sc;
        L[ci][l] = xb[(size_t)c * NPIX + p0 + l] * sc + sh;
    }
    __syncthreads();
    unsigned short* ob = xnbT + ((size_t)b * NPIX + p0) * CDIM + c0;
    #pragma unroll
    for (int i = 0; i < 16; ++i) {
        int pi = q * 16 + i;
        ob[(size_t)pi * CDIM + l] = f2bf(L[l][pi]);
    }
}

// ---------------------------------------------------------------------------
// Kernel 4: QKV GEMM, bf16 MFMA, fragments direct from L2 (R3-verified).
// Epilogue -> qkrm (Q pre-scaled by QSCALE) / vcm.
// ---------------------------------------------------------------------------
__global__ __launch_bounds__(256)
void qkv_gemm_kernel(const unsigned short* __restrict__ wqb,
                     const float* __restrict__ bias,
                     const unsigned short* __restrict__ xnbT,
                     unsigned short* __restrict__ qkrm,
                     unsigned short* __restrict__ vcm) {
    const int b = blockIdx.z;
    const int m0 = blockIdx.y * 128, p0 = blockIdx.x * 128;
    const int wave = threadIdx.x >> 6, lane = threadIdx.x & 63;
    const int ql = lane & 31, hi = lane >> 5;
    const int wr = wave >> 1, wc = wave & 1;

    const unsigned short* Abase = wqb + (size_t)(m0 + wr * 64) * CDIM;
    const unsigned short* Bbase = xnbT + ((size_t)b * NPIX + p0 + wc * 64) * CDIM;

    f32x16 acc[2][2] = {};
    #pragma unroll
    for (int k0 = 0; k0 < CDIM; k0 += 16) {
        bf16x8 a0 = *(const bf16x8*)(Abase + (size_t)(ql) * CDIM + k0 + hi * 8);
        bf16x8 a1 = *(const bf16x8*)(Abase + (size_t)(32 + ql) * CDIM + k0 + hi * 8);
        bf16x8 b0 = *(const bf16x8*)(Bbase + (size_t)(ql) * CDIM + k0 + hi * 8);
        bf16x8 b1 = *(const bf16x8*)(Bbase + (size_t)(32 + ql) * CDIM + k0 + hi * 8);
        acc[0][0] = __builtin_amdgcn_mfma_f32_32x32x16_bf16(a0, b0, acc[0][0], 0, 0, 0);
        acc[0][1] = __builtin_amdgcn_mfma_f32_32x32x16_bf16(a0, b1, acc[0][1], 0, 0, 0);
        acc[1][0] = __builtin_amdgcn_mfma_f32_32x32x16_bf16(a1, b0, acc[1][0], 0, 0, 0);
        acc[1][1] = __builtin_amdgcn_mfma_f32_32x32x16_bf16(a1, b1, acc[1][1], 0, 0, 0);
    }

    #pragma unroll
    for (int mt = 0; mt < 2; ++mt) {
        const int m_sub = m0 + wr * 64 + mt * 32;
        const int sel = m_sub >> 8;
        const int hh = (m_sub >> 5) & 7;
        #pragma unroll
        for (int pt = 0; pt < 2; ++pt) {
            const int p = p0 + wc * 64 + pt * 32 + ql;
            if (sel < 2) {
                const float qs = (sel == 0) ? QSCALE : 1.0f;
                unsigned short* qk = qkrm + (((size_t)b * 2 + sel) * NH + hh) * NPIX * HD;
                #pragma unroll
                for (int rg = 0; rg < 4; ++rg) {
                    const int dbase = rg * 8 + hi * 4;
                    ushort4v w;
                    #pragma unroll
                    for (int j = 0; j < 4; ++j)
                        w[j] = f2bf((acc[mt][pt][rg * 4 + j] + bias[m_sub + dbase + j]) * qs);
                    *(ushort4v*)(qk + (size_t)p * HD + dbase) = w;
                }
            } else {
                unsigned short* vc = vcm + ((size_t)b * NH + hh) * HD * NPIX;
                #pragma unroll
                for (int r = 0; r < 16; ++r) {
                    const int d = (r & 3) + 8 * (r >> 2) + 4 * hi;
                    vc[(size_t)d * NPIX + p] = f2bf(acc[mt][pt][r] + bias[m_sub + d]);
                }
            }
        }
    }
}

// ---------------------------------------------------------------------------
// Kernel 5: MFMA flash attention (R3-verified base). Single new element:
// row-sum on the matrix pipe (accl = P * ones, layout-proof since the ones
// B-fragment is identical under any layout), replacing the scalar lsum
// chain, the cross-half lsum add, and the 16-shuffle epilogue. Plus a pure
// fmaxf max3-shaped reduction tree.
// ---------------------------------------------------------------------------
__global__ __launch_bounds__(256)
void attn_mfma_kernel(const unsigned short* __restrict__ qkrm,
                      const unsigned short* __restrict__ vcm,
                      unsigned short* __restrict__ aoutT) {
    const int d = blockIdx.x;
    const int xcd = d & 7, i = d >> 3;
    const int qt = i & 7;
    const int pr = (xcd << 4) | (i >> 3);
    const int h = pr & 7, b = pr >> 3;

    const int tid = threadIdx.x;
    const int wave = tid >> 6, lane = tid & 63;
    const int ql = lane & 31, hi = lane >> 5;
    const int q0 = qt * 128 + wave * 32;

    const unsigned short* Qb = qkrm + (((size_t)b * 2 + 0) * NH + h) * NPIX * HD;
    const unsigned short* Kb = qkrm + (((size_t)b * 2 + 1) * NH + h) * NPIX * HD;
    const unsigned short* Vb = vcm  + ((size_t)b * NH + h) * HD * NPIX;

    __shared__ unsigned short Kl[2][64 * 40];
    __shared__ unsigned short Vl[2][32 * 72];

    bf16x8 qf0 = *(const bf16x8*)(Qb + (size_t)(q0 + ql) * HD + hi * 8);
    bf16x8 qf1 = *(const bf16x8*)(Qb + (size_t)(q0 + ql) * HD + 16 + hi * 8);

    bf16x8 onesv;
    #pragma unroll
    for (int z = 0; z < 8; ++z) onesv[z] = (short)0x3F80;   // bf16 1.0

    f32x16 acc = {};
    f32x16 accl = {};
    float mrun = -1e30f;

    const int krow = tid >> 2, kcol = (tid & 3) * 8;
    const int vrow = tid >> 3, vcol = (tid & 7) * 8;

    ushort8 kreg = *(const ushort8*)(Kb + (size_t)krow * HD + kcol);
    ushort8 vreg = *(const ushort8*)(Vb + (size_t)vrow * NPIX + vcol);
    *(ushort8*)&Kl[0][krow * 40 + kcol] = kreg;
    *(ushort8*)&Vl[0][vrow * 72 + vcol] = vreg;
    kreg = *(const ushort8*)(Kb + (size_t)(64 + krow) * HD + kcol);
    vreg = *(const ushort8*)(Vb + (size_t)vrow * NPIX + 64 + vcol);

    int cur = 0;
    for (int step = 0; step < 16; ++step) {
        __syncthreads();
        if (step + 1 < 16) {
            *(ushort8*)&Kl[cur ^ 1][krow * 40 + kcol] = kreg;
            *(ushort8*)&Vl[cur ^ 1][vrow * 72 + vcol] = vreg;
        }
        if (step + 2 < 16) {
            const int kv = (step + 2) * 64;
            kreg = *(const ushort8*)(Kb + (size_t)(kv + krow) * HD + kcol);
            vreg = *(const ushort8*)(Vb + (size_t)vrow * NPIX + kv + vcol);
        }

        #pragma unroll
        for (int u = 0; u < 2; ++u) {
            const unsigned short* Kr = &Kl[cur][(u * 32 + ql) * 40];
            bf16x8 kf0 = *(const bf16x8*)(Kr + hi * 8);
            bf16x8 kf1 = *(const bf16x8*)(Kr + 16 + hi * 8);
            f32x16 st = {};
            st = __builtin_amdgcn_mfma_f32_32x32x16_bf16(kf0, qf0, st, 0, 0, 0);
            st = __builtin_amdgcn_mfma_f32_32x32x16_bf16(kf1, qf1, st, 0, 0, 0);

            // max reduction tree (pure fmaxf, v_max3-shaped)
            float t0 = fmaxf(fmaxf(st[0], st[1]), st[2]);
            float t1 = fmaxf(fmaxf(st[3], st[4]), st[5]);
            float t2 = fmaxf(fmaxf(st[6], st[7]), st[8]);
            float t3 = fmaxf(fmaxf(st[9], st[10]), st[11]);
            float t4 = fmaxf(fmaxf(st[12], st[13]), st[14]);
            float vmax = fmaxf(fmaxf(fmaxf(t0, t1), t2), fmaxf(fmaxf(t3, t4), st[15]));
            float pmax = fmaxf(vmax, __shfl_xor(vmax, 32));
            if (!__all(pmax - mrun <= 11.5f)) {
                float mnew = fmaxf(mrun, pmax);
                float corr = exp2f(mrun - mnew);
                #pragma unroll
                for (int j = 0; j < 16; ++j) {
                    float cj = __shfl(corr, (j & 3) + 8 * (j >> 2) + 4 * hi);
                    acc[j]  *= cj;
                    accl[j] *= cj;
                }
                mrun = mnew;
            }
            float p[16];
            #pragma unroll
            for (int r = 0; r < 16; ++r) p[r] = exp2f(st[r] - mrun);

            // pack P to bf16 pairs (R3-verified asm cvt_pk)
            unsigned pk[8];
            #pragma unroll
            for (int k2 = 0; k2 < 8; ++k2) {
                unsigned r_;
                asm("v_cvt_pk_bf16_f32 %0, %1, %2" : "=v"(r_) : "v"(p[2 * k2]), "v"(p[2 * k2 + 1]));
                pk[k2] = r_;
            }
            // cross-half exchange (R3-verified shuffle + select mapping)
            unsigned x0 = __shfl_xor((int)pk[0], 32), x1 = __shfl_xor((int)pk[1], 32);
            unsigned x2 = __shfl_xor((int)pk[2], 32), x3 = __shfl_xor((int)pk[3], 32);
            unsigned x4 = __shfl_xor((int)pk[4], 32), x5 = __shfl_xor((int)pk[5], 32);
            unsigned x6 = __shfl_xor((int)pk[6], 32), x7 = __shfl_xor((int)pk[7], 32);
            union { unsigned u_[4]; bf16x8 v; } pa0, pa1;
            pa0.u_[0] = hi ? x2    : pk[0];
            pa0.u_[1] = hi ? x3    : pk[1];
            pa0.u_[2] = hi ? pk[2] : x0;
            pa0.u_[3] = hi ? pk[3] : x1;
            pa1.u_[0] = hi ? x6    : pk[4];
            pa1.u_[1] = hi ? x7    : pk[5];
            pa1.u_[2] = hi ? pk[6] : x4;
            pa1.u_[3] = hi ? pk[7] : x5;

            const unsigned short* Vr = &Vl[cur][ql * 72 + u * 32];
            bf16x8 vf0 = *(const bf16x8*)(Vr + hi * 8);
            bf16x8 vf1 = *(const bf16x8*)(Vr + 16 + hi * 8);
            acc  = __builtin_amdgcn_mfma_f32_32x32x16_bf16(pa0.v, vf0, acc, 0, 0, 0);
            acc  = __builtin_amdgcn_mfma_f32_32x32x16_bf16(pa1.v, vf1, acc, 0, 0, 0);
            // row-sum on the matrix pipe: accl = P * ones (same C-layout as acc)
            accl = __builtin_amdgcn_mfma_f32_32x32x16_bf16(pa0.v, onesv, accl, 0, 0, 0);
            accl = __builtin_amdgcn_mfma_f32_32x32x16_bf16(pa1.v, onesv, accl, 0, 0, 0);
        }
        cur ^= 1;
    }

    unsigned short* ob = aoutT + ((size_t)b * NPIX + q0) * CDIM + h * HD;
    #pragma unroll
    for (int j = 0; j < 16; ++j) {
        const int qr = (j & 3) + 8 * (j >> 2) + 4 * hi;
        const float inv_ = 1.0f / accl[j];
        ob[(size_t)qr * CDIM + ql] = f2bf(acc[j] * inv_);
    }
}

// ---------------------------------------------------------------------------
// Kernel 6: proj GEMM, bf16 MFMA + bias + fp32 residual (R3-verified).
// ---------------------------------------------------------------------------
__global__ __launch_bounds__(256)
void proj_gemm_kernel(const unsigned short* __restrict__ wpb,
                      const float* __restrict__ bias,
                      const unsigned short* __restrict__ aoutT,
                      const float* __restrict__ xres,
                      float* __restrict__ out) {
    const int b = blockIdx.z;
    const int m0 = blockIdx.y * 128, p0 = blockIdx.x * 128;
    const int wave = threadIdx.x >> 6, lane = threadIdx.x & 63;
    const int ql = lane & 31, hi = lane >> 5;
    const int wr = wave >> 1, wc = wave & 1;

    const unsigned short* Abase = wpb + (size_t)(m0 + wr * 64) * CDIM;
    const unsigned short* Bbase = aoutT + ((size_t)b * NPIX + p0 + wc * 64) * CDIM;

    f32x16 acc[2][2] = {};
    #pragma unroll
    for (int k0 = 0; k0 < CDIM; k0 += 16) {
        bf16x8 a0 = *(const bf16x8*)(Abase + (size_t)(ql) * CDIM + k0 + hi * 8);
        bf16x8 a1 = *(const bf16x8*)(Abase + (size_t)(32 + ql) * CDIM + k0 + hi * 8);
        bf16x8 b0 = *(const bf16x8*)(Bbase + (size_t)(ql) * CDIM + k0 + hi * 8);
        bf16x8 b1 = *(const bf16x8*)(Bbase + (size_t)(32 + ql) * CDIM + k0 + hi * 8);
        acc[0][0] = __builtin_amdgcn_mfma_f32_32x32x16_bf16(a0, b0, acc[0][0], 0, 0, 0);
        acc[0][1] = __builtin_amdgcn_mfma_f32_32x32x16_bf16(a0, b1, acc[0][1], 0, 0, 0);
        acc[1][0] = __builtin_amdgcn_mfma_f32_32x32x16_bf16(a1, b0, acc[1][0], 0, 0, 0);
        acc[1][1] = __builtin_amdgcn_mfma_f32_32x32x16_bf16(a1, b1, acc[1][1], 0, 0, 0);
    }

    #pragma unroll
    for (int mt = 0; mt < 2; ++mt) {
        const int m_sub = m0 + wr * 64 + mt * 32;
        #pragma unroll
        for (int pt = 0; pt < 2; ++pt) {
            const int p = p0 + wc * 64 + pt * 32 + ql;
            #pragma unroll
            for (int r = 0; r < 16; ++r) {
                const int m = m_sub + (r & 3) + 8 * (r >> 2) + 4 * hi;
                const size_t off = ((size_t)b * CDIM + m) * NPIX + p;
                out[off] = acc[mt][pt][r] + bias[m] + xres[off];
            }
        }
    }
}

// ---------------------------------------------------------------------------
extern "C" void kernel_launch(void* const* d_in, const int* in_sizes, int n_in,
                              void* d_out, int out_size, void* d_ws, size_t ws_size,
                              hipStream_t stream) {
    const float* x      = (const float*)d_in[0];
    const float* gn_w   = (const float*)d_in[1];
    const float* gn_b   = (const float*)d_in[2];
    const float* qkv_w  = (const float*)d_in[3];
    const float* qkv_b  = (const float*)d_in[4];
    const float* proj_w = (const float*)d_in[5];
    const float* proj_b = (const float*)d_in[6];
    float* out = (float*)d_out;

    char* ws = (char*)d_ws;
    size_t off = 0;
    float* partial = (float*)(ws + off); off += 2048;
    float* stats   = (float*)(ws + off); off += 512;
    unsigned short* wqb  = (unsigned short*)(ws + off); off += (size_t)768 * 256 * 2;
    unsigned short* wpb  = (unsigned short*)(ws + off); off += (size_t)256 * 256 * 2;
    unsigned short* xnbT = (unsigned short*)(ws + off); off += (size_t)NB * NPIX * CDIM * 2;
    unsigned short* qkrm = (unsigned short*)(ws + off); off += (size_t)NB * 2 * NH * NPIX * HD * 2;
    unsigned short* vcm  = (unsigned short*)(ws + off); off += (size_t)NB * NH * HD * NPIX * 2;
    unsigned short* aoutT = (unsigned short*)(ws + off);

    gn_partial_kernel<<<dim3(16, 16), 256, 0, stream>>>(x, partial);
    gn_final_kernel<<<16, 64, 0, stream>>>(partial, stats);
    wconv_kernel<<<256, 256, 0, stream>>>(qkv_w, proj_w, wqb, wpb);
    xnbt_kernel<<<dim3(16, 4, 16), 256, 0, stream>>>(x, gn_w, gn_b, stats, xnbT);

    qkv_gemm_kernel<<<dim3(NPIX / 128, 6, NB), 256, 0, stream>>>(
        wqb, qkv_b, xnbT, qkrm, vcm);

    attn_mfma_kernel<<<1024, 256, 0, stream>>>(qkrm, vcm, aoutT);

    proj_gemm_kernel<<<dim3(NPIX / 128, 2, NB), 256, 0, stream>>>(
        wpb, proj_b, aoutT, x, out);
}

// Round 8
// 194.376 us; speedup vs baseline: 1.0276x; 1.0276x over previous
//
#include <hip/hip_runtime.h>
#include <hip/hip_bf16.h>

typedef short bf16x8 __attribute__((ext_vector_type(8)));
typedef float f32x16 __attribute__((ext_vector_type(16)));
typedef unsigned short ushort8 __attribute__((ext_vector_type(8)));
typedef unsigned short ushort4v __attribute__((ext_vector_type(4)));

#define CDIM 256
#define NPIX 1024
#define NB 16
#define NH 8
#define HD 32
// scale * log2(e): softmax done in exp2 domain
#define QSCALE (0.17677669529663687f * 1.4426950408889634f)

// OCML native exp2: type-checked device function -> single v_exp_f32
extern "C" __device__ float __ocml_native_exp2_f32(float);
#define EXP2N(x) __ocml_native_exp2_f32(x)

static __device__ inline unsigned short f2bf(float f) {
    __hip_bfloat16 h = __float2bfloat16(f);
    return *reinterpret_cast<unsigned short*>(&h);
}

// ---------------------------------------------------------------------------
// Kernel 1a: partial sums for GroupNorm stats. grid (slice=16, b=16).
// ---------------------------------------------------------------------------
__global__ __launch_bounds__(256)
void gn_partial_kernel(const float* __restrict__ x, float* __restrict__ partial) {
    const int slice = blockIdx.x, b = blockIdx.y;
    const float4* xb = (const float4*)(x + (size_t)b * CDIM * NPIX + slice * 16384);
    const int tid = threadIdx.x;
    float s = 0.f, ss = 0.f;
    #pragma unroll
    for (int i = 0; i < 16; ++i) {
        float4 v = xb[tid + i * 256];
        s  += v.x + v.y + v.z + v.w;
        ss += v.x * v.x + v.y * v.y + v.z * v.z + v.w * v.w;
    }
    __shared__ float r0[256], r1[256];
    r0[tid] = s; r1[tid] = ss;
    __syncthreads();
    for (int st = 128; st > 0; st >>= 1) {
        if (tid < st) { r0[tid] += r0[tid + st]; r1[tid] += r1[tid + st]; }
        __syncthreads();
    }
    if (tid == 0) {
        partial[(b * 16 + slice) * 2 + 0] = r0[0];
        partial[(b * 16 + slice) * 2 + 1] = r1[0];
    }
}

// Kernel 1b: finalize stats. grid 16 blocks x 64 thr.
__global__ __launch_bounds__(64)
void gn_final_kernel(const float* __restrict__ partial, float* __restrict__ stats) {
    const int b = blockIdx.x, t = threadIdx.x;
    float s = 0.f, ss = 0.f;
    if (t < 16) { s = partial[(b * 16 + t) * 2]; ss = partial[(b * 16 + t) * 2 + 1]; }
    #pragma unroll
    for (int m = 8; m >= 1; m >>= 1) { s += __shfl_xor(s, m); ss += __shfl_xor(ss, m); }
    if (t == 0) {
        const float inv_n = 1.0f / (float)(CDIM * NPIX);
        float mean = s * inv_n;
        float var  = ss * inv_n - mean * mean;
        stats[b * 2 + 0] = mean;
        stats[b * 2 + 1] = rsqrtf(var + 1e-5f);
    }
}

// ---------------------------------------------------------------------------
// Kernel 2: weights f32 -> bf16 (qkv_w then proj_w).
// ---------------------------------------------------------------------------
__global__ __launch_bounds__(256)
void wconv_kernel(const float* __restrict__ qw, const float* __restrict__ pw,
                  unsigned short* __restrict__ wqb, unsigned short* __restrict__ wpb) {
    int idx = blockIdx.x * 256 + threadIdx.x;
    #pragma unroll
    for (int i = 0; i < 4; ++i) {
        int j = idx + i * 65536;
        if (j < 768 * 256) wqb[j] = f2bf(qw[j]);
        else               wpb[j - 768 * 256] = f2bf(pw[j - 768 * 256]);
    }
}

// ---------------------------------------------------------------------------
// Kernel 3: xnbT[b][p][c] bf16 = GroupNorm-affine(x[b][c][p]).  64x64 tiles.
// ---------------------------------------------------------------------------
__global__ __launch_bounds__(256)
void xnbt_kernel(const float* __restrict__ x, const float* __restrict__ gnw,
                 const float* __restrict__ gnb, const float* __restrict__ stats,
                 unsigned short* __restrict__ xnbT) {
    const int p0 = blockIdx.x * 64, c0 = blockIdx.y * 64, b = blockIdx.z;
    const int q = threadIdx.x >> 6, l = threadIdx.x & 63;
    const float mean = stats[b * 2], rstd = stats[b * 2 + 1];
    __shared__ float L[64][65];
    const float* xb = x + (size_t)b * CDIM * NPIX;
    #pragma unroll
    for (int i = 0; i < 16; ++i) {
        int ci = q * 16 + i;
        int c = c0 + ci;
        float sc = rstd * gnw[c];
        float sh = gnb[c] - mean * sc;
        L[ci][l] = xb[(size_t)c * NPIX + p0 + l] * sc + sh;
    }
    __syncthreads();
    unsigned short* ob = xnbT + ((size_t)b * NPIX + p0) * CDIM + c0;
    #pragma unroll
    for (int i = 0; i < 16; ++i) {
        int pi = q * 16 + i;
        ob[(size_t)pi * CDIM + l] = f2bf(L[l][pi]);
    }
}

// ---------------------------------------------------------------------------
// Kernel 4: staged bf16 MFMA GEMM (shared template for QKV and proj).
// Tile 128m x 128p, K=256 in 4 chunks of 64. A/B LDS rows padded to 72
// shorts (144B, 16B-aligned; <=4-way bank aliasing on read).
// EPI=1: QKV epilogue -> qkrm (Q pre-scaled) / vcm.   EPI=0: proj + resid.
// ---------------------------------------------------------------------------
template<int EPI>
__global__ __launch_bounds__(256)
void gemm_staged_kernel(const unsigned short* __restrict__ Wb,
                        const float* __restrict__ bias,
                        const unsigned short* __restrict__ Bsrc_all,
                        const float* __restrict__ xres,
                        float* __restrict__ out,
                        unsigned short* __restrict__ qkrm,
                        unsigned short* __restrict__ vcm) {
    const int b = blockIdx.z;
    const int m0 = blockIdx.y * 128, p0 = blockIdx.x * 128;
    const int tid = threadIdx.x;
    const int wave = tid >> 6, lane = tid & 63;
    const int ql = lane & 31, hi = lane >> 5;
    const int wr = wave >> 1, wc = wave & 1;

    __shared__ unsigned short As[128 * 72];   // 18432 B
    __shared__ unsigned short Bs[128 * 72];   // 18432 B

    const unsigned short* Asrc = Wb + (size_t)m0 * CDIM;
    const unsigned short* Bsrc = Bsrc_all + ((size_t)b * NPIX + p0) * CDIM;

    f32x16 acc[2][2] = {};
    for (int kc = 0; kc < 4; ++kc) {
        __syncthreads();   // protect previous chunk's reads
        #pragma unroll
        for (int i = 0; i < 4; ++i) {
            int chunk = i * 256 + tid;          // 1024 chunks of 8 shorts
            int row = chunk >> 3, c8 = chunk & 7;
            *(ushort8*)&As[row * 72 + c8 * 8] =
                *(const ushort8*)(Asrc + (size_t)row * CDIM + kc * 64 + c8 * 8);
            *(ushort8*)&Bs[row * 72 + c8 * 8] =
                *(const ushort8*)(Bsrc + (size_t)row * CDIM + kc * 64 + c8 * 8);
        }
        __syncthreads();
        #pragma unroll
        for (int k0 = 0; k0 < 64; k0 += 16) {
            bf16x8 a0 = *(const bf16x8*)&As[(wr * 64 + ql) * 72 + k0 + hi * 8];
            bf16x8 a1 = *(const bf16x8*)&As[(wr * 64 + 32 + ql) * 72 + k0 + hi * 8];
            bf16x8 b0 = *(const bf16x8*)&Bs[(wc * 64 + ql) * 72 + k0 + hi * 8];
            bf16x8 b1 = *(const bf16x8*)&Bs[(wc * 64 + 32 + ql) * 72 + k0 + hi * 8];
            acc[0][0] = __builtin_amdgcn_mfma_f32_32x32x16_bf16(a0, b0, acc[0][0], 0, 0, 0);
            acc[0][1] = __builtin_amdgcn_mfma_f32_32x32x16_bf16(a0, b1, acc[0][1], 0, 0, 0);
            acc[1][0] = __builtin_amdgcn_mfma_f32_32x32x16_bf16(a1, b0, acc[1][0], 0, 0, 0);
            acc[1][1] = __builtin_amdgcn_mfma_f32_32x32x16_bf16(a1, b1, acc[1][1], 0, 0, 0);
        }
    }

    // epilogues copied verbatim from the verified R6 kernels
    #pragma unroll
    for (int mt = 0; mt < 2; ++mt) {
        const int m_sub = m0 + wr * 64 + mt * 32;
        #pragma unroll
        for (int pt = 0; pt < 2; ++pt) {
            const int p = p0 + wc * 64 + pt * 32 + ql;
            if (EPI == 0) {
                #pragma unroll
                for (int r = 0; r < 16; ++r) {
                    const int m = m_sub + (r & 3) + 8 * (r >> 2) + 4 * hi;
                    const size_t off = ((size_t)b * CDIM + m) * NPIX + p;
                    out[off] = acc[mt][pt][r] + bias[m] + xres[off];
                }
            } else {
                const int sel = m_sub >> 8;
                const int hh = (m_sub >> 5) & 7;
                if (sel < 2) {
                    const float qs = (sel == 0) ? QSCALE : 1.0f;
                    unsigned short* qk = qkrm + (((size_t)b * 2 + sel) * NH + hh) * NPIX * HD;
                    #pragma unroll
                    for (int rg = 0; rg < 4; ++rg) {
                        const int dbase = rg * 8 + hi * 4;
                        ushort4v w;
                        #pragma unroll
                        for (int j = 0; j < 4; ++j)
                            w[j] = f2bf((acc[mt][pt][rg * 4 + j] + bias[m_sub + dbase + j]) * qs);
                        *(ushort4v*)(qk + (size_t)p * HD + dbase) = w;
                    }
                } else {
                    unsigned short* vc = vcm + ((size_t)b * NH + hh) * HD * NPIX;
                    #pragma unroll
                    for (int r = 0; r < 16; ++r) {
                        const int d = (r & 3) + 8 * (r >> 2) + 4 * hi;
                        vc[(size_t)d * NPIX + p] = f2bf(acc[mt][pt][r] + bias[m_sub + d]);
                    }
                }
            }
        }
    }
}

// ---------------------------------------------------------------------------
// Kernel 5: MFMA flash attention, KV-split. Block = 512 thr (8 waves):
// waves 0-3 (half 0) scan kv 0..511, waves 4-7 (half 1) scan kv 512..1023;
// each half double-buffers its own K/V LDS tiles. Final flash merge via an
// LDS overlay (comb) reusing the staging memory. Inner loop = R6-verified.
// ---------------------------------------------------------------------------
__global__ __launch_bounds__(512)
void attn_mfma_kernel(const unsigned short* __restrict__ qkrm,
                      const unsigned short* __restrict__ vcm,
                      unsigned short* __restrict__ aoutT) {
    const int d = blockIdx.x;
    const int xcd = d & 7, i = d >> 3;
    const int qt = i & 7;
    const int pr = (xcd << 4) | (i >> 3);
    const int h = pr & 7, b = pr >> 3;

    const int tid = threadIdx.x;
    const int wave = tid >> 6, lane = tid & 63;
    const int ql = lane & 31, hi = lane >> 5;
    const int half = tid >> 8;          // 0: kv 0-511, 1: kv 512-1023
    const int wq = wave & 3;            // q-subtile within the half
    const int q0 = qt * 128 + wq * 32;
    const int kvb = half * 512;

    // LDS: [half][dbuf] K tiles (64x40 shorts) then V tiles (32x72 shorts);
    // comb overlay (4 qtiles x 64 lanes x 33 floats = 33792 B) aliases it.
    __shared__ __align__(16) char smem[38912];
    float* comb = (float*)smem;

    const unsigned short* Qb = qkrm + (((size_t)b * 2 + 0) * NH + h) * NPIX * HD;
    const unsigned short* Kb = qkrm + (((size_t)b * 2 + 1) * NH + h) * NPIX * HD;
    const unsigned short* Vb = vcm  + ((size_t)b * NH + h) * HD * NPIX;

    bf16x8 qf0 = *(const bf16x8*)(Qb + (size_t)(q0 + ql) * HD + hi * 8);
    bf16x8 qf1 = *(const bf16x8*)(Qb + (size_t)(q0 + ql) * HD + 16 + hi * 8);

    bf16x8 onesv;
    #pragma unroll
    for (int z = 0; z < 8; ++z) onesv[z] = (short)0x3F80;   // bf16 1.0

    f32x16 acc = {};
    f32x16 accl = {};
    float mrun = -1e30f;

    const int t = tid & 255;
    const int krow = t >> 2, kcol = (t & 3) * 8;
    const int vrow = t >> 3, vcol = (t & 7) * 8;

    unsigned short* Kl[2];
    unsigned short* Vl[2];
    Kl[0] = (unsigned short*)(smem + (half * 2 + 0) * 5120);
    Kl[1] = (unsigned short*)(smem + (half * 2 + 1) * 5120);
    Vl[0] = (unsigned short*)(smem + 20480 + (half * 2 + 0) * 4608);
    Vl[1] = (unsigned short*)(smem + 20480 + (half * 2 + 1) * 4608);

    ushort8 kreg = *(const ushort8*)(Kb + (size_t)(kvb + krow) * HD + kcol);
    ushort8 vreg = *(const ushort8*)(Vb + (size_t)vrow * NPIX + kvb + vcol);
    *(ushort8*)&Kl[0][krow * 40 + kcol] = kreg;
    *(ushort8*)&Vl[0][vrow * 72 + vcol] = vreg;
    kreg = *(const ushort8*)(Kb + (size_t)(kvb + 64 + krow) * HD + kcol);
    vreg = *(const ushort8*)(Vb + (size_t)vrow * NPIX + kvb + 64 + vcol);

    int cur = 0;
    for (int step = 0; step < 8; ++step) {
        __syncthreads();
        if (step + 1 < 8) {
            *(ushort8*)&Kl[cur ^ 1][krow * 40 + kcol] = kreg;
            *(ushort8*)&Vl[cur ^ 1][vrow * 72 + vcol] = vreg;
        }
        if (step + 2 < 8) {
            const int kv = kvb + (step + 2) * 64;
            kreg = *(const ushort8*)(Kb + (size_t)(kv + krow) * HD + kcol);
            vreg = *(const ushort8*)(Vb + (size_t)vrow * NPIX + kv + vcol);
        }

        #pragma unroll
        for (int u = 0; u < 2; ++u) {
            const unsigned short* Kr = &Kl[cur][(u * 32 + ql) * 40];
            bf16x8 kf0 = *(const bf16x8*)(Kr + hi * 8);
            bf16x8 kf1 = *(const bf16x8*)(Kr + 16 + hi * 8);
            f32x16 st = {};
            st = __builtin_amdgcn_mfma_f32_32x32x16_bf16(kf0, qf0, st, 0, 0, 0);
            st = __builtin_amdgcn_mfma_f32_32x32x16_bf16(kf1, qf1, st, 0, 0, 0);

            float t0 = fmaxf(fmaxf(st[0], st[1]), st[2]);
            float t1 = fmaxf(fmaxf(st[3], st[4]), st[5]);
            float t2 = fmaxf(fmaxf(st[6], st[7]), st[8]);
            float t3 = fmaxf(fmaxf(st[9], st[10]), st[11]);
            float t4 = fmaxf(fmaxf(st[12], st[13]), st[14]);
            float vmax = fmaxf(fmaxf(fmaxf(t0, t1), t2), fmaxf(fmaxf(t3, t4), st[15]));
            float pmax = fmaxf(vmax, __shfl_xor(vmax, 32));
            if (!__all(pmax - mrun <= 11.5f)) {
                float mnew = fmaxf(mrun, pmax);
                float corr = EXP2N(mrun - mnew);
                #pragma unroll
                for (int j = 0; j < 16; ++j) {
                    float cj = __shfl(corr, (j & 3) + 8 * (j >> 2) + 4 * hi);
                    acc[j]  *= cj;
                    accl[j] *= cj;
                }
                mrun = mnew;
            }
            float p[16];
            #pragma unroll
            for (int r = 0; r < 16; ++r) p[r] = EXP2N(st[r] - mrun);

            unsigned pk[8];
            #pragma unroll
            for (int k2 = 0; k2 < 8; ++k2) {
                unsigned r_;
                asm("v_cvt_pk_bf16_f32 %0, %1, %2" : "=v"(r_) : "v"(p[2 * k2]), "v"(p[2 * k2 + 1]));
                pk[k2] = r_;
            }
            unsigned x0 = __shfl_xor((int)pk[0], 32), x1 = __shfl_xor((int)pk[1], 32);
            unsigned x2 = __shfl_xor((int)pk[2], 32), x3 = __shfl_xor((int)pk[3], 32);
            unsigned x4 = __shfl_xor((int)pk[4], 32), x5 = __shfl_xor((int)pk[5], 32);
            unsigned x6 = __shfl_xor((int)pk[6], 32), x7 = __shfl_xor((int)pk[7], 32);
            union { unsigned u_[4]; bf16x8 v; } pa0, pa1;
            pa0.u_[0] = hi ? x2    : pk[0];
            pa0.u_[1] = hi ? x3    : pk[1];
            pa0.u_[2] = hi ? pk[2] : x0;
            pa0.u_[3] = hi ? pk[3] : x1;
            pa1.u_[0] = hi ? x6    : pk[4];
            pa1.u_[1] = hi ? x7    : pk[5];
            pa1.u_[2] = hi ? pk[6] : x4;
            pa1.u_[3] = hi ? pk[7] : x5;

            const unsigned short* Vr = &Vl[cur][ql * 72 + u * 32];
            bf16x8 vf0 = *(const bf16x8*)(Vr + hi * 8);
            bf16x8 vf1 = *(const bf16x8*)(Vr + 16 + hi * 8);
            acc  = __builtin_amdgcn_mfma_f32_32x32x16_bf16(pa0.v, vf0, acc, 0, 0, 0);
            acc  = __builtin_amdgcn_mfma_f32_32x32x16_bf16(pa1.v, vf1, acc, 0, 0, 0);
            accl = __builtin_amdgcn_mfma_f32_32x32x16_bf16(pa0.v, onesv, accl, 0, 0, 0);
            accl = __builtin_amdgcn_mfma_f32_32x32x16_bf16(pa1.v, onesv, accl, 0, 0, 0);
        }
        cur ^= 1;
    }

    // ---- flash merge of the two halves through the comb overlay ----
    __syncthreads();   // all staging-buffer reads complete before overlay
    if (half == 1) {
        float* cb = comb + ((size_t)wq * 64 + lane) * 33;
        #pragma unroll
        for (int j = 0; j < 16; ++j) cb[j] = acc[j];
        #pragma unroll
        for (int j = 0; j < 16; ++j) cb[16 + j] = accl[j];
        cb[32] = mrun;
    }
    __syncthreads();
    if (half == 0) {
        const float* cb = comb + ((size_t)wq * 64 + lane) * 33;
        float m1 = cb[32];
        float mstar = fmaxf(mrun, m1);
        float f0 = EXP2N(mrun - mstar);
        float f1 = EXP2N(m1 - mstar);
        unsigned short* ob = aoutT + ((size_t)b * NPIX + q0) * CDIM + h * HD;
        #pragma unroll
        for (int j = 0; j < 16; ++j) {
            const int qr = (j & 3) + 8 * (j >> 2) + 4 * hi;
            float f0j = __shfl(f0, qr);
            float f1j = __shfl(f1, qr);
            float a  = acc[j]  * f0j + cb[j]      * f1j;
            float l  = accl[j] * f0j + cb[16 + j] * f1j;
            ob[(size_t)qr * CDIM + ql] = f2bf(a * (1.0f / l));
        }
    }
}

// ---------------------------------------------------------------------------
extern "C" void kernel_launch(void* const* d_in, const int* in_sizes, int n_in,
                              void* d_out, int out_size, void* d_ws, size_t ws_size,
                              hipStream_t stream) {
    const float* x      = (const float*)d_in[0];
    const float* gn_w   = (const float*)d_in[1];
    const float* gn_b   = (const float*)d_in[2];
    const float* qkv_w  = (const float*)d_in[3];
    const float* qkv_b  = (const float*)d_in[4];
    const float* proj_w = (const float*)d_in[5];
    const float* proj_b = (const float*)d_in[6];
    float* out = (float*)d_out;

    char* ws = (char*)d_ws;
    size_t off = 0;
    float* partial = (float*)(ws + off); off += 2048;
    float* stats   = (float*)(ws + off); off += 512;
    unsigned short* wqb  = (unsigned short*)(ws + off); off += (size_t)768 * 256 * 2;
    unsigned short* wpb  = (unsigned short*)(ws + off); off += (size_t)256 * 256 * 2;
    unsigned short* xnbT = (unsigned short*)(ws + off); off += (size_t)NB * NPIX * CDIM * 2;
    unsigned short* qkrm = (unsigned short*)(ws + off); off += (size_t)NB * 2 * NH * NPIX * HD * 2;
    unsigned short* vcm  = (unsigned short*)(ws + off); off += (size_t)NB * NH * HD * NPIX * 2;
    unsigned short* aoutT = (unsigned short*)(ws + off);

    gn_partial_kernel<<<dim3(16, 16), 256, 0, stream>>>(x, partial);
    gn_final_kernel<<<16, 64, 0, stream>>>(partial, stats);
    wconv_kernel<<<256, 256, 0, stream>>>(qkv_w, proj_w, wqb, wpb);
    xnbt_kernel<<<dim3(16, 4, 16), 256, 0, stream>>>(x, gn_w, gn_b, stats, xnbT);

    gemm_staged_kernel<1><<<dim3(NPIX / 128, 6, NB), 256, 0, stream>>>(
        wqb, qkv_b, xnbT, nullptr, nullptr, qkrm, vcm);

    attn_mfma_kernel<<<1024, 512, 0, stream>>>(qkrm, vcm, aoutT);

    gemm_staged_kernel<0><<<dim3(NPIX / 128, 2, NB), 256, 0, stream>>>(
        wpb, proj_b, aoutT, x, out, nullptr, nullptr);
}

// Round 10
// 191.244 us; speedup vs baseline: 1.0444x; 1.0164x over previous
//
#include <hip/hip_runtime.h>
#include <hip/hip_bf16.h>

typedef short bf16x8 __attribute__((ext_vector_type(8)));
typedef float f32x16 __attribute__((ext_vector_type(16)));
typedef unsigned short ushort8 __attribute__((ext_vector_type(8)));
typedef unsigned short ushort4v __attribute__((ext_vector_type(4)));

#define CDIM 256
#define NPIX 1024
#define NB 16
#define NH 8
#define HD 32
// scale * log2(e): softmax done in exp2 domain
#define QSCALE (0.17677669529663687f * 1.4426950408889634f)

// OCML native exp2: type-checked device function -> single v_exp_f32
extern "C" __device__ float __ocml_native_exp2_f32(float);
#define EXP2N(x) __ocml_native_exp2_f32(x)

static __device__ inline unsigned short f2bf(float f) {
    __hip_bfloat16 h = __float2bfloat16(f);
    return *reinterpret_cast<unsigned short*>(&h);
}

// ---------------------------------------------------------------------------
// Kernel 1a (THE ONE CHANGE THIS ROUND): partial sums for GroupNorm stats.
// grid (slice=64, b=16) = 1024 blocks (4/CU). 4096-float slice per block.
// ---------------------------------------------------------------------------
__global__ __launch_bounds__(256)
void gn_partial_kernel(const float* __restrict__ x, float* __restrict__ partial) {
    const int slice = blockIdx.x, b = blockIdx.y;
    const float4* xb = (const float4*)(x + (size_t)b * CDIM * NPIX + slice * 4096);
    const int tid = threadIdx.x;
    float s = 0.f, ss = 0.f;
    #pragma unroll
    for (int i = 0; i < 4; ++i) {
        float4 v = xb[tid + i * 256];
        s  += v.x + v.y + v.z + v.w;
        ss += v.x * v.x + v.y * v.y + v.z * v.z + v.w * v.w;
    }
    __shared__ float r0[256], r1[256];
    r0[tid] = s; r1[tid] = ss;
    __syncthreads();
    for (int st = 128; st > 0; st >>= 1) {
        if (tid < st) { r0[tid] += r0[tid + st]; r1[tid] += r1[tid + st]; }
        __syncthreads();
    }
    if (tid == 0) {
        partial[(b * 64 + slice) * 2 + 0] = r0[0];
        partial[(b * 64 + slice) * 2 + 1] = r1[0];
    }
}

// ---------------------------------------------------------------------------
// Kernel 1b+2 fused (part of the same change): blocks 0-255 convert weights
// f32->bf16; blocks 256-271 finalize stats (64 partials/sample, wave reduce).
// ---------------------------------------------------------------------------
__global__ __launch_bounds__(256)
void gnfinal_wconv_kernel(const float* __restrict__ qw, const float* __restrict__ pw,
                          unsigned short* __restrict__ wqb, unsigned short* __restrict__ wpb,
                          const float* __restrict__ partial, float* __restrict__ stats) {
    const int blk = blockIdx.x;
    const int tid = threadIdx.x;
    if (blk < 256) {
        int idx = blk * 256 + tid;
        #pragma unroll
        for (int i = 0; i < 4; ++i) {
            int j = idx + i * 65536;
            if (j < 768 * 256) wqb[j] = f2bf(qw[j]);
            else               wpb[j - 768 * 256] = f2bf(pw[j - 768 * 256]);
        }
    } else if (tid < 64) {
        const int b = blk - 256, t = tid;
        float s = partial[(b * 64 + t) * 2], ss = partial[(b * 64 + t) * 2 + 1];
        #pragma unroll
        for (int m = 32; m >= 1; m >>= 1) { s += __shfl_xor(s, m); ss += __shfl_xor(ss, m); }
        if (t == 0) {
            const float inv_n = 1.0f / (float)(CDIM * NPIX);
            float mean = s * inv_n;
            float var  = ss * inv_n - mean * mean;
            stats[b * 2 + 0] = mean;
            stats[b * 2 + 1] = rsqrtf(var + 1e-5f);
        }
    }
}

// ---------------------------------------------------------------------------
// Kernel 3: xnbT[b][p][c] bf16 = GroupNorm-affine(x[b][c][p]).  (R7 verbatim)
// ---------------------------------------------------------------------------
__global__ __launch_bounds__(256)
void xnbt_kernel(const float* __restrict__ x, const float* __restrict__ gnw,
                 const float* __restrict__ gnb, const float* __restrict__ stats,
                 unsigned short* __restrict__ xnbT) {
    const int p0 = blockIdx.x * 64, c0 = blockIdx.y * 64, b = blockIdx.z;
    const int q = threadIdx.x >> 6, l = threadIdx.x & 63;
    const float mean = stats[b * 2], rstd = stats[b * 2 + 1];
    __shared__ float L[64][65];
    const float* xb = x + (size_t)b * CDIM * NPIX;
    #pragma unroll
    for (int i = 0; i < 16; ++i) {
        int ci = q * 16 + i;
        int c = c0 + ci;
        float sc = rstd * gnw[c];
        float sh = gnb[c] - mean * sc;
        L[ci][l] = xb[(size_t)c * NPIX + p0 + l] * sc + sh;
    }
    __syncthreads();
    unsigned short* ob = xnbT + ((size_t)b * NPIX + p0) * CDIM + c0;
    #pragma unroll
    for (int i = 0; i < 16; ++i) {
        int pi = q * 16 + i;
        ob[(size_t)pi * CDIM + l] = f2bf(L[l][pi]);
    }
}

// ---------------------------------------------------------------------------
// Kernel 4: staged bf16 MFMA GEMM (R7 verbatim).
// ---------------------------------------------------------------------------
template<int EPI>
__global__ __launch_bounds__(256)
void gemm_staged_kernel(const unsigned short* __restrict__ Wb,
                        const float* __restrict__ bias,
                        const unsigned short* __restrict__ Bsrc_all,
                        const float* __restrict__ xres,
                        float* __restrict__ out,
                        unsigned short* __restrict__ qkrm,
                        unsigned short* __restrict__ vcm) {
    const int b = blockIdx.z;
    const int m0 = blockIdx.y * 128, p0 = blockIdx.x * 128;
    const int tid = threadIdx.x;
    const int wave = tid >> 6, lane = tid & 63;
    const int ql = lane & 31, hi = lane >> 5;
    const int wr = wave >> 1, wc = wave & 1;

    __shared__ unsigned short As[128 * 72];
    __shared__ unsigned short Bs[128 * 72];

    const unsigned short* Asrc = Wb + (size_t)m0 * CDIM;
    const unsigned short* Bsrc = Bsrc_all + ((size_t)b * NPIX + p0) * CDIM;

    f32x16 acc[2][2] = {};
    for (int kc = 0; kc < 4; ++kc) {
        __syncthreads();
        #pragma unroll
        for (int i = 0; i < 4; ++i) {
            int chunk = i * 256 + tid;
            int row = chunk >> 3, c8 = chunk & 7;
            *(ushort8*)&As[row * 72 + c8 * 8] =
                *(const ushort8*)(Asrc + (size_t)row * CDIM + kc * 64 + c8 * 8);
            *(ushort8*)&Bs[row * 72 + c8 * 8] =
                *(const ushort8*)(Bsrc + (size_t)row * CDIM + kc * 64 + c8 * 8);
        }
        __syncthreads();
        #pragma unroll
        for (int k0 = 0; k0 < 64; k0 += 16) {
            bf16x8 a0 = *(const bf16x8*)&As[(wr * 64 + ql) * 72 + k0 + hi * 8];
            bf16x8 a1 = *(const bf16x8*)&As[(wr * 64 + 32 + ql) * 72 + k0 + hi * 8];
            bf16x8 b0 = *(const bf16x8*)&Bs[(wc * 64 + ql) * 72 + k0 + hi * 8];
            bf16x8 b1 = *(const bf16x8*)&Bs[(wc * 64 + 32 + ql) * 72 + k0 + hi * 8];
            acc[0][0] = __builtin_amdgcn_mfma_f32_32x32x16_bf16(a0, b0, acc[0][0], 0, 0, 0);
            acc[0][1] = __builtin_amdgcn_mfma_f32_32x32x16_bf16(a0, b1, acc[0][1], 0, 0, 0);
            acc[1][0] = __builtin_amdgcn_mfma_f32_32x32x16_bf16(a1, b0, acc[1][0], 0, 0, 0);
            acc[1][1] = __builtin_amdgcn_mfma_f32_32x32x16_bf16(a1, b1, acc[1][1], 0, 0, 0);
        }
    }

    #pragma unroll
    for (int mt = 0; mt < 2; ++mt) {
        const int m_sub = m0 + wr * 64 + mt * 32;
        #pragma unroll
        for (int pt = 0; pt < 2; ++pt) {
            const int p = p0 + wc * 64 + pt * 32 + ql;
            if (EPI == 0) {
                #pragma unroll
                for (int r = 0; r < 16; ++r) {
                    const int m = m_sub + (r & 3) + 8 * (r >> 2) + 4 * hi;
                    const size_t off = ((size_t)b * CDIM + m) * NPIX + p;
                    out[off] = acc[mt][pt][r] + bias[m] + xres[off];
                }
            } else {
                const int sel = m_sub >> 8;
                const int hh = (m_sub >> 5) & 7;
                if (sel < 2) {
                    const float qs = (sel == 0) ? QSCALE : 1.0f;
                    unsigned short* qk = qkrm + (((size_t)b * 2 + sel) * NH + hh) * NPIX * HD;
                    #pragma unroll
                    for (int rg = 0; rg < 4; ++rg) {
                        const int dbase = rg * 8 + hi * 4;
                        ushort4v w;
                        #pragma unroll
                        for (int j = 0; j < 4; ++j)
                            w[j] = f2bf((acc[mt][pt][rg * 4 + j] + bias[m_sub + dbase + j]) * qs);
                        *(ushort4v*)(qk + (size_t)p * HD + dbase) = w;
                    }
                } else {
                    unsigned short* vc = vcm + ((size_t)b * NH + hh) * HD * NPIX;
                    #pragma unroll
                    for (int r = 0; r < 16; ++r) {
                        const int d = (r & 3) + 8 * (r >> 2) + 4 * hi;
                        vc[(size_t)d * NPIX + p] = f2bf(acc[mt][pt][r] + bias[m_sub + d]);
                    }
                }
            }
        }
    }
}

// ---------------------------------------------------------------------------
// Kernel 5: MFMA flash attention, KV-split (R7 verbatim — passed at 63.5us).
// ---------------------------------------------------------------------------
__global__ __launch_bounds__(512)
void attn_mfma_kernel(const unsigned short* __restrict__ qkrm,
                      const unsigned short* __restrict__ vcm,
                      unsigned short* __restrict__ aoutT) {
    const int d = blockIdx.x;
    const int xcd = d & 7, i = d >> 3;
    const int qt = i & 7;
    const int pr = (xcd << 4) | (i >> 3);
    const int h = pr & 7, b = pr >> 3;

    const int tid = threadIdx.x;
    const int wave = tid >> 6, lane = tid & 63;
    const int ql = lane & 31, hi = lane >> 5;
    const int half = tid >> 8;          // 0: kv 0-511, 1: kv 512-1023
    const int wq = wave & 3;            // q-subtile within the half
    const int q0 = qt * 128 + wq * 32;
    const int kvb = half * 512;

    __shared__ __align__(16) char smem[38912];
    float* comb = (float*)smem;

    const unsigned short* Qb = qkrm + (((size_t)b * 2 + 0) * NH + h) * NPIX * HD;
    const unsigned short* Kb = qkrm + (((size_t)b * 2 + 1) * NH + h) * NPIX * HD;
    const unsigned short* Vb = vcm  + ((size_t)b * NH + h) * HD * NPIX;

    bf16x8 qf0 = *(const bf16x8*)(Qb + (size_t)(q0 + ql) * HD + hi * 8);
    bf16x8 qf1 = *(const bf16x8*)(Qb + (size_t)(q0 + ql) * HD + 16 + hi * 8);

    bf16x8 onesv;
    #pragma unroll
    for (int z = 0; z < 8; ++z) onesv[z] = (short)0x3F80;   // bf16 1.0

    f32x16 acc = {};
    f32x16 accl = {};
    float mrun = -1e30f;

    const int t = tid & 255;
    const int krow = t >> 2, kcol = (t & 3) * 8;
    const int vrow = t >> 3, vcol = (t & 7) * 8;

    unsigned short* Kl[2];
    unsigned short* Vl[2];
    Kl[0] = (unsigned short*)(smem + (half * 2 + 0) * 5120);
    Kl[1] = (unsigned short*)(smem + (half * 2 + 1) * 5120);
    Vl[0] = (unsigned short*)(smem + 20480 + (half * 2 + 0) * 4608);
    Vl[1] = (unsigned short*)(smem + 20480 + (half * 2 + 1) * 4608);

    ushort8 kreg = *(const ushort8*)(Kb + (size_t)(kvb + krow) * HD + kcol);
    ushort8 vreg = *(const ushort8*)(Vb + (size_t)vrow * NPIX + kvb + vcol);
    *(ushort8*)&Kl[0][krow * 40 + kcol] = kreg;
    *(ushort8*)&Vl[0][vrow * 72 + vcol] = vreg;
    kreg = *(const ushort8*)(Kb + (size_t)(kvb + 64 + krow) * HD + kcol);
    vreg = *(const ushort8*)(Vb + (size_t)vrow * NPIX + kvb + 64 + vcol);

    int cur = 0;
    for (int step = 0; step < 8; ++step) {
        __syncthreads();
        if (step + 1 < 8) {
            *(ushort8*)&Kl[cur ^ 1][krow * 40 + kcol] = kreg;
            *(ushort8*)&Vl[cur ^ 1][vrow * 72 + vcol] = vreg;
        }
        if (step + 2 < 8) {
            const int kv = kvb + (step + 2) * 64;
            kreg = *(const ushort8*)(Kb + (size_t)(kv + krow) * HD + kcol);
            vreg = *(const ushort8*)(Vb + (size_t)vrow * NPIX + kv + vcol);
        }

        #pragma unroll
        for (int u = 0; u < 2; ++u) {
            const unsigned short* Kr = &Kl[cur][(u * 32 + ql) * 40];
            bf16x8 kf0 = *(const bf16x8*)(Kr + hi * 8);
            bf16x8 kf1 = *(const bf16x8*)(Kr + 16 + hi * 8);
            f32x16 st = {};
            st = __builtin_amdgcn_mfma_f32_32x32x16_bf16(kf0, qf0, st, 0, 0, 0);
            st = __builtin_amdgcn_mfma_f32_32x32x16_bf16(kf1, qf1, st, 0, 0, 0);

            float t0 = fmaxf(fmaxf(st[0], st[1]), st[2]);
            float t1 = fmaxf(fmaxf(st[3], st[4]), st[5]);
            float t2 = fmaxf(fmaxf(st[6], st[7]), st[8]);
            float t3 = fmaxf(fmaxf(st[9], st[10]), st[11]);
            float t4 = fmaxf(fmaxf(st[12], st[13]), st[14]);
            float vmax = fmaxf(fmaxf(fmaxf(t0, t1), t2), fmaxf(fmaxf(t3, t4), st[15]));
            float pmax = fmaxf(vmax, __shfl_xor(vmax, 32));
            if (!__all(pmax - mrun <= 11.5f)) {
                float mnew = fmaxf(mrun, pmax);
                float corr = EXP2N(mrun - mnew);
                #pragma unroll
                for (int j = 0; j < 16; ++j) {
                    float cj = __shfl(corr, (j & 3) + 8 * (j >> 2) + 4 * hi);
                    acc[j]  *= cj;
                    accl[j] *= cj;
                }
                mrun = mnew;
            }
            float p[16];
            #pragma unroll
            for (int r = 0; r < 16; ++r) p[r] = EXP2N(st[r] - mrun);

            unsigned pk[8];
            #pragma unroll
            for (int k2 = 0; k2 < 8; ++k2) {
                unsigned r_;
                asm("v_cvt_pk_bf16_f32 %0, %1, %2" : "=v"(r_) : "v"(p[2 * k2]), "v"(p[2 * k2 + 1]));
                pk[k2] = r_;
            }
            unsigned x0 = __shfl_xor((int)pk[0], 32), x1 = __shfl_xor((int)pk[1], 32);
            unsigned x2 = __shfl_xor((int)pk[2], 32), x3 = __shfl_xor((int)pk[3], 32);
            unsigned x4 = __shfl_xor((int)pk[4], 32), x5 = __shfl_xor((int)pk[5], 32);
            unsigned x6 = __shfl_xor((int)pk[6], 32), x7 = __shfl_xor((int)pk[7], 32);
            union { unsigned u_[4]; bf16x8 v; } pa0, pa1;
            pa0.u_[0] = hi ? x2    : pk[0];
            pa0.u_[1] = hi ? x3    : pk[1];
            pa0.u_[2] = hi ? pk[2] : x0;
            pa0.u_[3] = hi ? pk[3] : x1;
            pa1.u_[0] = hi ? x6    : pk[4];
            pa1.u_[1] = hi ? x7    : pk[5];
            pa1.u_[2] = hi ? pk[6] : x4;
            pa1.u_[3] = hi ? pk[7] : x5;

            const unsigned short* Vr = &Vl[cur][ql * 72 + u * 32];
            bf16x8 vf0 = *(const bf16x8*)(Vr + hi * 8);
            bf16x8 vf1 = *(const bf16x8*)(Vr + 16 + hi * 8);
            acc  = __builtin_amdgcn_mfma_f32_32x32x16_bf16(pa0.v, vf0, acc, 0, 0, 0);
            acc  = __builtin_amdgcn_mfma_f32_32x32x16_bf16(pa1.v, vf1, acc, 0, 0, 0);
            accl = __builtin_amdgcn_mfma_f32_32x32x16_bf16(pa0.v, onesv, accl, 0, 0, 0);
            accl = __builtin_amdgcn_mfma_f32_32x32x16_bf16(pa1.v, onesv, accl, 0, 0, 0);
        }
        cur ^= 1;
    }

    // ---- flash merge of the two halves through the comb overlay ----
    __syncthreads();
    if (half == 1) {
        float* cb = comb + ((size_t)wq * 64 + lane) * 33;
        #pragma unroll
        for (int j = 0; j < 16; ++j) cb[j] = acc[j];
        #pragma unroll
        for (int j = 0; j < 16; ++j) cb[16 + j] = accl[j];
        cb[32] = mrun;
    }
    __syncthreads();
    if (half == 0) {
        const float* cb = comb + ((size_t)wq * 64 + lane) * 33;
        float m1 = cb[32];
        float mstar = fmaxf(mrun, m1);
        float f0 = EXP2N(mrun - mstar);
        float f1 = EXP2N(m1 - mstar);
        unsigned short* ob = aoutT + ((size_t)b * NPIX + q0) * CDIM + h * HD;
        #pragma unroll
        for (int j = 0; j < 16; ++j) {
            const int qr = (j & 3) + 8 * (j >> 2) + 4 * hi;
            float f0j = __shfl(f0, qr);
            float f1j = __shfl(f1, qr);
            float a  = acc[j]  * f0j + cb[j]      * f1j;
            float l  = accl[j] * f0j + cb[16 + j] * f1j;
            ob[(size_t)qr * CDIM + ql] = f2bf(a * (1.0f / l));
        }
    }
}

// ---------------------------------------------------------------------------
extern "C" void kernel_launch(void* const* d_in, const int* in_sizes, int n_in,
                              void* d_out, int out_size, void* d_ws, size_t ws_size,
                              hipStream_t stream) {
    const float* x      = (const float*)d_in[0];
    const float* gn_w   = (const float*)d_in[1];
    const float* gn_b   = (const float*)d_in[2];
    const float* qkv_w  = (const float*)d_in[3];
    const float* qkv_b  = (const float*)d_in[4];
    const float* proj_w = (const float*)d_in[5];
    const float* proj_b = (const float*)d_in[6];
    float* out = (float*)d_out;

    char* ws = (char*)d_ws;
    size_t off = 0;
    float* partial = (float*)(ws + off); off += 16 * 64 * 2 * 4;
    float* stats   = (float*)(ws + off); off += 512;
    unsigned short* wqb  = (unsigned short*)(ws + off); off += (size_t)768 * 256 * 2;
    unsigned short* wpb  = (unsigned short*)(ws + off); off += (size_t)256 * 256 * 2;
    unsigned short* xnbT = (unsigned short*)(ws + off); off += (size_t)NB * NPIX * CDIM * 2;
    unsigned short* qkrm = (unsigned short*)(ws + off); off += (size_t)NB * 2 * NH * NPIX * HD * 2;
    unsigned short* vcm  = (unsigned short*)(ws + off); off += (size_t)NB * NH * HD * NPIX * 2;
    unsigned short* aoutT = (unsigned short*)(ws + off);

    gn_partial_kernel<<<dim3(64, 16), 256, 0, stream>>>(x, partial);
    gnfinal_wconv_kernel<<<272, 256, 0, stream>>>(qkv_w, proj_w, wqb, wpb, partial, stats);
    xnbt_kernel<<<dim3(16, 4, 16), 256, 0, stream>>>(x, gn_w, gn_b, stats, xnbT);

    gemm_staged_kernel<1><<<dim3(NPIX / 128, 6, NB), 256, 0, stream>>>(
        wqb, qkv_b, xnbT, nullptr, nullptr, qkrm, vcm);

    attn_mfma_kernel<<<1024, 512, 0, stream>>>(qkrm, vcm, aoutT);

    gemm_staged_kernel<0><<<dim3(NPIX / 128, 2, NB), 256, 0, stream>>>(
        wpb, proj_b, aoutT, x, out, nullptr, nullptr);
}